// Round 7
// baseline (84.470 us; speedup 1.0000x reference)
//
#include <hip/hip_runtime.h>

#define BB 16
#define CC 256
#define TT 512
#define CCH 2              // channels per block
#define FPT 8              // frames per thread
#define NTH 256
#define FT (NTH * FPT)     // 2048 frames per block -> covers L in one tile

typedef float f32x4 __attribute__((ext_vector_type(4)));

// Fully fused LengthRegulator. Each block: recompute the cheap per-batch scan,
// scatter frame->phoneme ids into LDS, stage 2 x-rows in LDS, gather +
// zero-fill with nontemporal float4 stores. x is fetched exactly once.
__global__ __launch_bounds__(NTH) void lr_fused_kernel(
    const float* __restrict__ x,     // [B, C, T]
    const int* __restrict__ dur,     // [B, T]
    float* __restrict__ out,         // [B, C, L] ++ mel_len[B] (as float)
    int L)
{
    __shared__ int   lds_idx[FT];          // 8 KB
    __shared__ float lds_x[CCH * TT];      // 4 KB
    __shared__ int   wsum[NTH / 64];

    const int tid   = threadIdx.x;
    const int b     = blockIdx.z;
    const int c0    = blockIdx.y * CCH;
    const int fbase = blockIdx.x * FT;

    // init idx table (padding frames must hold a valid index; masked to 0 later)
    *(int4*)(lds_idx + tid * 8)     = make_int4(0, 0, 0, 0);
    *(int4*)(lds_idx + tid * 8 + 4) = make_int4(0, 0, 0, 0);

    // ---- block-local inclusive scan of dur[b, :] (2 elems/thread) ----
    int2 dp = *(const int2*)(dur + b * TT + tid * 2);
    const int d0 = dp.x < 0 ? 0 : dp.x;
    const int d1 = dp.y < 0 ? 0 : dp.y;
    int v = d0 + d1;                        // pair sum
    #pragma unroll
    for (int off = 1; off < 64; off <<= 1) {
        int o = __shfl_up(v, off, 64);
        if ((tid & 63) >= off) v += o;
    }
    const int wid = tid >> 6;
    if ((tid & 63) == 63) wsum[wid] = v;

    // ---- stage x rows (2 rows = 1024 contiguous floats) while scan settles ----
    const float* __restrict__ xb = x + ((size_t)b * CC + c0) * TT;
    *(float4*)(lds_x + tid * 4) = *(const float4*)(xb + tid * 4);

    __syncthreads();

    int woff = 0, ml = 0;
    #pragma unroll
    for (int w = 0; w < NTH / 64; ++w) {
        const int s = wsum[w];
        if (w < wid) woff += s;
        ml += s;
    }
    const int cum1   = woff + v;            // inclusive cum of phoneme 2t+1
    const int cum0   = cum1 - d1;           // inclusive cum of phoneme 2t
    const int start0 = cum0 - d0;

    // scatter phoneme ids into lds_idx (clip to this f-tile; 1 tile when FT>=L)
    const int fend = fbase + FT;
    {
        int lo = start0 > fbase ? start0 : fbase;
        int hi = cum0 < fend ? cum0 : fend;
        for (int f = lo; f < hi; ++f) lds_idx[f - fbase] = tid * 2;
        lo = cum0 > fbase ? cum0 : fbase;
        hi = cum1 < fend ? cum1 : fend;
        for (int f = lo; f < hi; ++f) lds_idx[f - fbase] = tid * 2 + 1;
    }
    __syncthreads();

    // ---- gather from LDS + zero-fill + nontemporal store ----
    const int f0 = fbase + tid * FPT;
    if (f0 < L) {
        float* __restrict__ ob = out + ((size_t)b * CC + c0) * (size_t)L + f0;
        if (((L & 3) == 0) && (f0 + FPT <= L)) {
            const int4 ia = *(const int4*)(lds_idx + tid * FPT);
            const int4 ib = *(const int4*)(lds_idx + tid * FPT + 4);
            const bool m0 = (f0 + 0) < ml, m1 = (f0 + 1) < ml;
            const bool m2 = (f0 + 2) < ml, m3 = (f0 + 3) < ml;
            const bool m4 = (f0 + 4) < ml, m5 = (f0 + 5) < ml;
            const bool m6 = (f0 + 6) < ml, m7 = (f0 + 7) < ml;
            #pragma unroll
            for (int cc = 0; cc < CCH; ++cc) {
                const float* __restrict__ xr = lds_x + cc * TT;
                f32x4 oa, obv;
                oa.x  = m0 ? xr[ia.x] : 0.0f;
                oa.y  = m1 ? xr[ia.y] : 0.0f;
                oa.z  = m2 ? xr[ia.z] : 0.0f;
                oa.w  = m3 ? xr[ia.w] : 0.0f;
                obv.x = m4 ? xr[ib.x] : 0.0f;
                obv.y = m5 ? xr[ib.y] : 0.0f;
                obv.z = m6 ? xr[ib.z] : 0.0f;
                obv.w = m7 ? xr[ib.w] : 0.0f;
                __builtin_nontemporal_store(oa,  (f32x4*)(ob + (size_t)cc * L));
                __builtin_nontemporal_store(obv, (f32x4*)(ob + (size_t)cc * L + 4));
            }
        } else {
            const int nf = (L - f0) < FPT ? (L - f0) : FPT;
            for (int cc = 0; cc < CCH; ++cc) {
                const float* __restrict__ xr = lds_x + cc * TT;
                for (int j = 0; j < nf; ++j) {
                    const int f  = f0 + j;
                    const int id = lds_idx[tid * FPT + j];
                    ob[(size_t)cc * L + j] = (f < ml) ? xr[id] : 0.0f;
                }
            }
        }
    }

    // mel_len (as float32) — one block per batch writes it
    if (blockIdx.x == 0 && blockIdx.y == 0 && tid == 0)
        out[(size_t)BB * CC * L + b] = (float)ml;
}

extern "C" void kernel_launch(void* const* d_in, const int* in_sizes, int n_in,
                              void* d_out, int out_size, void* d_ws, size_t ws_size,
                              hipStream_t stream)
{
    const float* x = (const float*)d_in[0];
    const int* dur = (const int*)d_in[1];
    float* out     = (float*)d_out;

    // out = [B, C, L] floats ++ mel_len[B]  =>  L = (out_size - B) / (B*C)
    const int L = (out_size - BB) / (BB * CC);

    dim3 grid((L + FT - 1) / FT, CC / CCH, BB);
    lr_fused_kernel<<<grid, NTH, 0, stream>>>(x, dur, out, L);
}

// Round 8
// 77.832 us; speedup vs baseline: 1.0853x; 1.0853x over previous
//
#include <hip/hip_runtime.h>

#define BB 16
#define CC 256
#define TT 512
#define CCH 2              // channels per block
#define NTH 256
#define FT 2048            // frames per block; 2 halves of 1024, 4 frames/thread each

typedef float f32x4 __attribute__((ext_vector_type(4)));

// Fully fused LengthRegulator. Each block: recompute the cheap per-batch scan,
// scatter frame->phoneme ids into LDS, stage 2 x-rows in LDS, gather +
// zero-fill. Stores are contiguous 16B/lane (1KB per wave-store), nontemporal.
__global__ __launch_bounds__(NTH) void lr_fused_kernel(
    const float* __restrict__ x,     // [B, C, T]
    const int* __restrict__ dur,     // [B, T]
    float* __restrict__ out,         // [B, C, L] ++ mel_len[B] (as float)
    int L)
{
    __shared__ int   lds_idx[FT];          // 8 KB
    __shared__ float lds_x[CCH * TT];      // 4 KB
    __shared__ int   wsum[NTH / 64];

    const int tid   = threadIdx.x;
    const int b     = blockIdx.z;
    const int c0    = blockIdx.y * CCH;
    const int fbase = blockIdx.x * FT;

    // init idx table (padding frames must hold a valid index; masked to 0 later)
    *(int4*)(lds_idx + tid * 8)     = make_int4(0, 0, 0, 0);
    *(int4*)(lds_idx + tid * 8 + 4) = make_int4(0, 0, 0, 0);

    // ---- block-local inclusive scan of dur[b, :] (2 elems/thread) ----
    int2 dp = *(const int2*)(dur + b * TT + tid * 2);
    const int d0 = dp.x < 0 ? 0 : dp.x;
    const int d1 = dp.y < 0 ? 0 : dp.y;
    int v = d0 + d1;                        // pair sum
    #pragma unroll
    for (int off = 1; off < 64; off <<= 1) {
        int o = __shfl_up(v, off, 64);
        if ((tid & 63) >= off) v += o;
    }
    const int wid = tid >> 6;
    if ((tid & 63) == 63) wsum[wid] = v;

    // ---- stage x rows (2 rows = 1024 contiguous floats) while scan settles ----
    const float* __restrict__ xb = x + ((size_t)b * CC + c0) * TT;
    *(float4*)(lds_x + tid * 4) = *(const float4*)(xb + tid * 4);

    __syncthreads();

    int woff = 0, ml = 0;
    #pragma unroll
    for (int w = 0; w < NTH / 64; ++w) {
        const int s = wsum[w];
        if (w < wid) woff += s;
        ml += s;
    }
    const int cum1   = woff + v;            // inclusive cum of phoneme 2t+1
    const int cum0   = cum1 - d1;           // inclusive cum of phoneme 2t
    const int start0 = cum0 - d0;

    // scatter phoneme ids into lds_idx (clip to this f-tile; 1 tile when FT>=L)
    const int fend = fbase + FT;
    {
        int lo = start0 > fbase ? start0 : fbase;
        int hi = cum0 < fend ? cum0 : fend;
        for (int f = lo; f < hi; ++f) lds_idx[f - fbase] = tid * 2;
        lo = cum0 > fbase ? cum0 : fbase;
        hi = cum1 < fend ? cum1 : fend;
        for (int f = lo; f < hi; ++f) lds_idx[f - fbase] = tid * 2 + 1;
    }
    __syncthreads();

    // ---- gather from LDS + zero-fill + store: 2 contiguous 1024-frame halves,
    //      4 consecutive frames/thread -> dense 1KB-per-wave stores ----
    #pragma unroll
    for (int h = 0; h < 2; ++h) {
        const int foff = h * 1024 + tid * 4;        // offset within tile
        const int f0   = fbase + foff;              // global frame
        if (f0 >= L) continue;
        float* __restrict__ ob = out + ((size_t)b * CC + c0) * (size_t)L + f0;
        if (((L & 3) == 0)) {                       // f0+4 <= L since L%4==0
            const int4 id4 = *(const int4*)(lds_idx + foff);
            const bool m0 = (f0 + 0) < ml, m1 = (f0 + 1) < ml;
            const bool m2 = (f0 + 2) < ml, m3 = (f0 + 3) < ml;
            #pragma unroll
            for (int cc = 0; cc < CCH; ++cc) {
                const float* __restrict__ xr = lds_x + cc * TT;
                f32x4 o;
                o.x = m0 ? xr[id4.x] : 0.0f;
                o.y = m1 ? xr[id4.y] : 0.0f;
                o.z = m2 ? xr[id4.z] : 0.0f;
                o.w = m3 ? xr[id4.w] : 0.0f;
                __builtin_nontemporal_store(o, (f32x4*)(ob + (size_t)cc * L));
            }
        } else {
            const int nf = (L - f0) < 4 ? (L - f0) : 4;
            for (int cc = 0; cc < CCH; ++cc) {
                const float* __restrict__ xr = lds_x + cc * TT;
                for (int j = 0; j < nf; ++j) {
                    const int f  = f0 + j;
                    const int id = lds_idx[foff + j];
                    ob[(size_t)cc * L + j] = (f < ml) ? xr[id] : 0.0f;
                }
            }
        }
    }

    // mel_len (as float32) — one block per batch writes it
    if (blockIdx.x == 0 && blockIdx.y == 0 && tid == 0)
        out[(size_t)BB * CC * L + b] = (float)ml;
}

extern "C" void kernel_launch(void* const* d_in, const int* in_sizes, int n_in,
                              void* d_out, int out_size, void* d_ws, size_t ws_size,
                              hipStream_t stream)
{
    const float* x = (const float*)d_in[0];
    const int* dur = (const int*)d_in[1];
    float* out     = (float*)d_out;

    // out = [B, C, L] floats ++ mel_len[B]  =>  L = (out_size - B) / (B*C)
    const int L = (out_size - BB) / (BB * CC);

    dim3 grid((L + FT - 1) / FT, CC / CCH, BB);
    lr_fused_kernel<<<grid, NTH, 0, stream>>>(x, dur, out, L);
}

// Round 11
// 77.349 us; speedup vs baseline: 1.0921x; 1.0062x over previous
//
#include <hip/hip_runtime.h>

#define BB 16
#define CC 256
#define TT 512
#define CCH 2              // channels per block
#define NTH 256
#define FT 2048            // frames per block; 2 halves of 1024, 4 frames/thread each

typedef float f32x4 __attribute__((ext_vector_type(4)));

// Fully fused LengthRegulator. Each block: recompute the cheap per-batch scan,
// scatter frame->phoneme ids into LDS, stage 2 x-rows in LDS, gather +
// zero-fill. Stores are contiguous 16B/lane (1KB per wave-store), regular
// (not nontemporal): 30MB output = 3.75MB/XCD fits dirty in L2.
__global__ __launch_bounds__(NTH) void lr_fused_kernel(
    const float* __restrict__ x,     // [B, C, T]
    const int* __restrict__ dur,     // [B, T]
    float* __restrict__ out,         // [B, C, L] ++ mel_len[B] (as float)
    int L)
{
    __shared__ int   lds_idx[FT];          // 8 KB
    __shared__ float lds_x[CCH * TT];      // 4 KB
    __shared__ int   wsum[NTH / 64];

    const int tid   = threadIdx.x;
    const int b     = blockIdx.z;
    const int c0    = blockIdx.y * CCH;
    const int fbase = blockIdx.x * FT;

    // issue global loads first (dur then x) so latency hides under setup
    int2 dp = *(const int2*)(dur + b * TT + tid * 2);
    const float* __restrict__ xb = x + ((size_t)b * CC + c0) * TT;
    const float4 xv = *(const float4*)(xb + tid * 4);

    // init idx table (padding frames must hold a valid index; masked to 0 later)
    *(int4*)(lds_idx + tid * 8)     = make_int4(0, 0, 0, 0);
    *(int4*)(lds_idx + tid * 8 + 4) = make_int4(0, 0, 0, 0);

    // ---- block-local inclusive scan of dur[b, :] (2 elems/thread) ----
    const int d0 = dp.x < 0 ? 0 : dp.x;
    const int d1 = dp.y < 0 ? 0 : dp.y;
    int v = d0 + d1;                        // pair sum
    #pragma unroll
    for (int off = 1; off < 64; off <<= 1) {
        int o = __shfl_up(v, off, 64);
        if ((tid & 63) >= off) v += o;
    }
    const int wid = tid >> 6;
    if ((tid & 63) == 63) wsum[wid] = v;

    // stage x rows (2 rows = 1024 contiguous floats)
    *(float4*)(lds_x + tid * 4) = xv;

    __syncthreads();

    int woff = 0, ml = 0;
    #pragma unroll
    for (int w = 0; w < NTH / 64; ++w) {
        const int s = wsum[w];
        if (w < wid) woff += s;
        ml += s;
    }
    const int cum1   = woff + v;            // inclusive cum of phoneme 2t+1
    const int cum0   = cum1 - d1;           // inclusive cum of phoneme 2t
    const int start0 = cum0 - d0;

    // scatter phoneme ids into lds_idx (clip to this f-tile; 1 tile when FT>=L)
    const int fend = fbase + FT;
    {
        int lo = start0 > fbase ? start0 : fbase;
        int hi = cum0 < fend ? cum0 : fend;
        for (int f = lo; f < hi; ++f) lds_idx[f - fbase] = tid * 2;
        lo = cum0 > fbase ? cum0 : fbase;
        hi = cum1 < fend ? cum1 : fend;
        for (int f = lo; f < hi; ++f) lds_idx[f - fbase] = tid * 2 + 1;
    }
    __syncthreads();

    // ---- gather from LDS + zero-fill + store: 2 contiguous 1024-frame halves,
    //      4 consecutive frames/thread -> dense 1KB-per-wave stores ----
    #pragma unroll
    for (int h = 0; h < 2; ++h) {
        const int foff = h * 1024 + tid * 4;        // offset within tile
        const int f0   = fbase + foff;              // global frame
        if (f0 >= L) continue;
        float* __restrict__ ob = out + ((size_t)b * CC + c0) * (size_t)L + f0;
        if (((L & 3) == 0)) {                       // f0+4 <= L since L%4==0
            const int4 id4 = *(const int4*)(lds_idx + foff);
            const bool m0 = (f0 + 0) < ml, m1 = (f0 + 1) < ml;
            const bool m2 = (f0 + 2) < ml, m3 = (f0 + 3) < ml;
            #pragma unroll
            for (int cc = 0; cc < CCH; ++cc) {
                const float* __restrict__ xr = lds_x + cc * TT;
                f32x4 o;
                o.x = m0 ? xr[id4.x] : 0.0f;
                o.y = m1 ? xr[id4.y] : 0.0f;
                o.z = m2 ? xr[id4.z] : 0.0f;
                o.w = m3 ? xr[id4.w] : 0.0f;
                *(f32x4*)(ob + (size_t)cc * L) = o;
            }
        } else {
            const int nf = (L - f0) < 4 ? (L - f0) : 4;
            for (int cc = 0; cc < CCH; ++cc) {
                const float* __restrict__ xr = lds_x + cc * TT;
                for (int j = 0; j < nf; ++j) {
                    const int f  = f0 + j;
                    const int id = lds_idx[foff + j];
                    ob[(size_t)cc * L + j] = (f < ml) ? xr[id] : 0.0f;
                }
            }
        }
    }

    // mel_len (as float32) — one block per batch writes it
    if (blockIdx.x == 0 && blockIdx.y == 0 && tid == 0)
        out[(size_t)BB * CC * L + b] = (float)ml;
}

extern "C" void kernel_launch(void* const* d_in, const int* in_sizes, int n_in,
                              void* d_out, int out_size, void* d_ws, size_t ws_size,
                              hipStream_t stream)
{
    const float* x = (const float*)d_in[0];
    const int* dur = (const int*)d_in[1];
    float* out     = (float*)d_out;

    // out = [B, C, L] floats ++ mel_len[B]  =>  L = (out_size - B) / (B*C)
    const int L = (out_size - BB) / (BB * CC);

    dim3 grid((L + FT - 1) / FT, CC / CCH, BB);
    lr_fused_kernel<<<grid, NTH, 0, stream>>>(x, dur, out, L);
}